// Round 1
// 200.755 us; speedup vs baseline: 1.0340x; 1.0340x over previous
//
#include <hip/hip_runtime.h>

#define ALPHA_F 1000.0f

typedef _Float16 half8 __attribute__((ext_vector_type(8)));
typedef float floatx4 __attribute__((ext_vector_type(4)));

__device__ __forceinline__ void gload_lds16(const void* g, void* l) {
    __builtin_amdgcn_global_load_lds(
        (const __attribute__((address_space(1))) unsigned int*)g,
        (__attribute__((address_space(3))) unsigned int*)l, 16, 0, 0);
}

// ============ fused prep: W_enc/W_dec/creps splits + cnorm (unchanged) =====
__global__ __launch_bounds__(256) void prep(
    const float* __restrict__ W_enc, const float* __restrict__ W_dec,
    const float* __restrict__ creps,
    _Float16* __restrict__ Wh, _Float16* __restrict__ Wl,
    _Float16* __restrict__ Wdh,
    _Float16* __restrict__ Ch, _Float16* __restrict__ Cl,
    float* __restrict__ cnorm)
{
    const int bid = blockIdx.x;
    if (bid < 256) {
        const int q = bid * 256 + threadIdx.x;
        const int n = q & 255, k8 = q >> 8;
        const int k = k8 * 8;
        half8 h, l;
        #pragma unroll
        for (int i = 0; i < 8; ++i) {
            const float v = W_enc[(size_t)(k + i) * 256 + n] * 256.0f;
            const _Float16 hi = (_Float16)v;
            h[i] = hi;
            l[i] = (_Float16)(v - (float)hi);
        }
        const int kc = k >> 5, nt = n >> 4;
        const int lane = (n & 15) | ((k8 & 3) << 4);
        const size_t idx = (size_t)((kc * 16 + nt) * 64 + lane) * 8;
        *(half8*)(Wh + idx) = h;
        *(half8*)(Wl + idx) = l;
    } else if (bid < 512) {
        const int q = (bid - 256) * 256 + threadIdx.x;
        const int n = q & 2047, k8 = q >> 11;
        const int k = k8 * 8;
        half8 h;
        #pragma unroll
        for (int i = 0; i < 8; ++i) h[i] = (_Float16)W_dec[(size_t)(k + i) * 2048 + n];
        const int kc = k8 >> 2, nt = n >> 4;
        const int lane = (n & 15) | ((k8 & 3) << 4);
        *(half8*)(Wdh + (size_t)((kc * 128 + nt) * 64 + lane) * 8) = h;
    } else if (bid < 544) {
        const int q = (bid - 512) * 256 + threadIdx.x;
        const int n = q & 255, j8 = q >> 8;
        const int j = j8 * 8;
        half8 h, l;
        #pragma unroll
        for (int i = 0; i < 8; ++i) {
            const float v = creps[(size_t)n * 256 + j + i];
            const _Float16 hi = (_Float16)v;
            h[i] = hi;
            l[i] = (_Float16)((v - (float)hi) * 2048.0f);
        }
        const int jc = j >> 5, nt = n >> 4;
        const int lane = (n & 15) | ((j8 & 3) << 4);
        const size_t idx = (size_t)((jc * 16 + nt) * 64 + lane) * 8;
        *(half8*)(Ch + idx) = h;
        *(half8*)(Cl + idx) = l;
    } else {
        const int wid = threadIdx.x >> 6, lane = threadIdx.x & 63;
        const int row = (bid - 544) * 4 + wid;
        const float4 v = *(const float4*)(creps + (size_t)row * 256 + lane * 4);
        float s = v.x * v.x + v.y * v.y + v.z * v.z + v.w * v.w;
        #pragma unroll
        for (int off = 32; off >= 1; off >>= 1) s += __shfl_xor(s, off, 64);
        if (lane == 0) cnorm[row] = s;
    }
}

// ============ emb partials — double-buffered single-barrier pipeline ========
// Arithmetic (MFMA chains, operand order, split formulas, P layout) identical
// to the r3 version; only the schedule changed:
//   old: loadX -> bar -> stage+writeA -> bar -> frags+MFMA   (2 bars, 0 overlap)
//   new: prefetch x(t+1)+stage B(t+1) -> frags(t)+MFMA(t) -> writeA(t+1) -> bar
// One barrier per K-step; stage latency hides under 48 MFMAs.
__global__ __launch_bounds__(256) void emb_gemm(
    const float* __restrict__ x, const _Float16* __restrict__ Wh,
    const _Float16* __restrict__ Wl, float* __restrict__ P)
{
    __shared__ _Float16 Ah[2][4 * 64 * 8], Al[2][4 * 64 * 8];
    __shared__ _Float16 Bh[2][16 * 64 * 8], Bl[2][16 * 64 * 8];
    const int t = threadIdx.x, lane = t & 63, w = t >> 6;
    const int kk = blockIdx.x;
    const int mb = blockIdx.y;
    const int m0 = mb * 64;

    const int am = t >> 2, q = t & 3;
    const int aoff = (((am >> 4) * 64) + ((am & 15) | (q << 4))) * 8;
    const float* xP = x + (size_t)(m0 + am) * 2048 + kk * 512 + q * 8;

    floatx4 acc[4][4] = {};

    // --- prologue: fill buffer 0 ---
    {
        const float4 v0 = *(const float4*)(xP);
        const float4 v1 = *(const float4*)(xP + 4);
        const int kc = kk * 16;
        const _Float16* bh_src = Wh + (size_t)kc * 16 * 512;
        const _Float16* bl_src = Wl + (size_t)kc * 16 * 512;
        #pragma unroll
        for (int i = 0; i < 4; ++i) {
            const int c = w * 4 + i;
            gload_lds16(bh_src + (size_t)c * 512 + lane * 8, &Bh[0][c * 512]);
            gload_lds16(bl_src + (size_t)c * 512 + lane * 8, &Bl[0][c * 512]);
        }
        const float vv[8] = {v0.x, v0.y, v0.z, v0.w, v1.x, v1.y, v1.z, v1.w};
        half8 h8, l8;
        #pragma unroll
        for (int i = 0; i < 8; ++i) {
            const _Float16 hi = (_Float16)vv[i];
            h8[i] = hi;
            l8[i] = (_Float16)(vv[i] - (float)hi);
        }
        *(half8*)(&Ah[0][aoff]) = h8;
        *(half8*)(&Al[0][aoff]) = l8;
        __syncthreads();
    }

    for (int it = 0; it < 16; ++it) {
        const int buf = it & 1;

        // prefetch next tile: x -> regs, W -> LDS (other buffer), both in-flight
        float4 n0, n1;
        if (it < 15) {
            n0 = *(const float4*)(xP + (it + 1) * 32);
            n1 = *(const float4*)(xP + (it + 1) * 32 + 4);
            const int kc = kk * 16 + it + 1;
            const _Float16* bh_src = Wh + (size_t)kc * 16 * 512;
            const _Float16* bl_src = Wl + (size_t)kc * 16 * 512;
            #pragma unroll
            for (int i = 0; i < 4; ++i) {
                const int c = w * 4 + i;
                gload_lds16(bh_src + (size_t)c * 512 + lane * 8, &Bh[buf ^ 1][c * 512]);
                gload_lds16(bl_src + (size_t)c * 512 + lane * 8, &Bl[buf ^ 1][c * 512]);
            }
        }

        // current tile: frags + MFMA (identical chain order to r3)
        half8 ah[4], al[4], bh[4], bl[4];
        #pragma unroll
        for (int s = 0; s < 4; ++s) {
            ah[s] = *(const half8*)(&Ah[buf][(s * 64 + lane) * 8]);
            al[s] = *(const half8*)(&Al[buf][(s * 64 + lane) * 8]);
        }
        #pragma unroll
        for (int ni = 0; ni < 4; ++ni) {
            bh[ni] = *(const half8*)(&Bh[buf][((w * 4 + ni) * 64 + lane) * 8]);
            bl[ni] = *(const half8*)(&Bl[buf][((w * 4 + ni) * 64 + lane) * 8]);
        }
        #pragma unroll
        for (int mi = 0; mi < 4; ++mi) {
            #pragma unroll
            for (int ni = 0; ni < 4; ++ni) {
                acc[mi][ni] = __builtin_amdgcn_mfma_f32_16x16x32_f16(ah[mi], bl[ni], acc[mi][ni], 0, 0, 0);
                acc[mi][ni] = __builtin_amdgcn_mfma_f32_16x16x32_f16(al[mi], bh[ni], acc[mi][ni], 0, 0, 0);
                acc[mi][ni] = __builtin_amdgcn_mfma_f32_16x16x32_f16(ah[mi], bh[ni], acc[mi][ni], 0, 0, 0);
            }
        }

        // convert + write next A tile, then the single barrier (drains vmcnt
        // for the B stage too — its latency was hidden under the MFMAs above)
        if (it < 15) {
            const float vv[8] = {n0.x, n0.y, n0.z, n0.w, n1.x, n1.y, n1.z, n1.w};
            half8 h8, l8;
            #pragma unroll
            for (int i = 0; i < 8; ++i) {
                const _Float16 hi = (_Float16)vv[i];
                h8[i] = hi;
                l8[i] = (_Float16)(vv[i] - (float)hi);
            }
            *(half8*)(&Ah[buf ^ 1][aoff]) = h8;
            *(half8*)(&Al[buf ^ 1][aoff]) = l8;
            __syncthreads();
        }
    }

    float* Pk = P + (size_t)kk * 2097152;
    #pragma unroll
    for (int mi = 0; mi < 4; ++mi) {
        #pragma unroll
        for (int ni = 0; ni < 4; ++ni) {
            const int col = w * 64 + ni * 16 + (lane & 15);
            const int rowBase = m0 + mi * 16 + (lane >> 4) * 4;
            #pragma unroll
            for (int r = 0; r < 4; ++r)
                Pk[(size_t)(rowBase + r) * 256 + col] = acc[mi][ni][r];
        }
    }
}

// ============ finalize (unchanged) ==========================================
__global__ __launch_bounds__(256) void finalize(
    const float* __restrict__ P, const float* __restrict__ b_enc,
    _Float16* __restrict__ ehg, float* __restrict__ embf,
    float* __restrict__ enorm)
{
    const int t = threadIdx.x;
    const int b0 = blockIdx.x * 32;
    const int row = t >> 3, c8 = t & 7;
    const int grow = b0 + row;

    const float* p0 = P + (size_t)grow * 256 + c8 * 32;
    float4 v[8];
    #pragma unroll
    for (int i = 0; i < 8; ++i) v[i] = *(const float4*)(p0 + i * 4);
    #pragma unroll
    for (int kk = 1; kk < 4; ++kk) {
        const float* pk = p0 + (size_t)kk * 2097152;
        #pragma unroll
        for (int i = 0; i < 8; ++i) {
            const float4 a = *(const float4*)(pk + i * 4);
            v[i].x += a.x; v[i].y += a.y; v[i].z += a.z; v[i].w += a.w;
        }
    }
    const float inv = 1.0f / 256.0f;
    float e[32];
    float ssq = 0.0f;
    #pragma unroll
    for (int i = 0; i < 8; ++i) {
        const float4 b = *(const float4*)(b_enc + c8 * 32 + i * 4);
        e[i * 4 + 0] = v[i].x * inv + b.x;
        e[i * 4 + 1] = v[i].y * inv + b.y;
        e[i * 4 + 2] = v[i].z * inv + b.z;
        e[i * 4 + 3] = v[i].w * inv + b.w;
        ssq += e[i * 4 + 0] * e[i * 4 + 0];
        ssq += e[i * 4 + 1] * e[i * 4 + 1];
        ssq += e[i * 4 + 2] * e[i * 4 + 2];
        ssq += e[i * 4 + 3] * e[i * 4 + 3];
    }
    #pragma unroll
    for (int i = 0; i < 8; ++i) {
        float4 s4;
        s4.x = e[i * 4 + 0]; s4.y = e[i * 4 + 1];
        s4.z = e[i * 4 + 2]; s4.w = e[i * 4 + 3];
        *(float4*)(embf + (size_t)grow * 256 + c8 * 32 + i * 4) = s4;
    }
    #pragma unroll
    for (int oo = 0; oo < 4; ++oo) {
        const int q = c8 * 4 + oo;
        half8 h;
        #pragma unroll
        for (int i = 0; i < 8; ++i) h[i] = (_Float16)e[oo * 8 + i];
        const size_t idx = (size_t)(((grow >> 4) * 8 + (q >> 2)) * 64
                                    + ((grow & 15) | ((q & 3) << 4))) * 8;
        *(half8*)(ehg + idx) = h;
    }
    ssq += __shfl_xor(ssq, 1, 64);
    ssq += __shfl_xor(ssq, 2, 64);
    ssq += __shfl_xor(ssq, 4, 64);
    if (c8 == 0) enorm[grow] = ssq;
}

// ============ dist + softmin (unchanged) ====================================
__global__ __launch_bounds__(256) void dist16(
    const float* __restrict__ embf, const _Float16* __restrict__ ch,
    const _Float16* __restrict__ cl, const float* __restrict__ enorm,
    const float* __restrict__ cnorm, float* __restrict__ out)
{
    __shared__ float D[16 * 257];
    __shared__ float MINV[16], SUMV[16];
    const int t = threadIdx.x, lane = t & 63, w = t >> 6;
    const int b0 = blockIdx.x * 16;
    const int arow16 = lane & 15, aoct = lane >> 4;

    floatx4 acc[4] = {}, accX[4] = {};
    for (int kc = 0; kc < 8; ++kc) {
        const float* fp = embf + (size_t)(b0 + arow16) * 256 + kc * 32 + aoct * 8;
        const float4 u0 = *(const float4*)(fp);
        const float4 u1 = *(const float4*)(fp + 4);
        const float vv[8] = {u0.x, u0.y, u0.z, u0.w, u1.x, u1.y, u1.z, u1.w};
        half8 ah, al;
        #pragma unroll
        for (int j = 0; j < 8; ++j) {
            const _Float16 hi = (_Float16)vv[j];
            ah[j] = hi;
            al[j] = (_Float16)((vv[j] - (float)hi) * 2048.0f);
        }
        #pragma unroll
        for (int ni = 0; ni < 4; ++ni) {
            const size_t bb = (size_t)((kc * 16 + (w * 4 + ni)) * 64 + lane) * 8;
            const half8 bh = *(const half8*)(ch + bb);
            const half8 bl = *(const half8*)(cl + bb);
            acc[ni]  = __builtin_amdgcn_mfma_f32_16x16x32_f16(ah, bh, acc[ni], 0, 0, 0);
            accX[ni] = __builtin_amdgcn_mfma_f32_16x16x32_f16(ah, bl, accX[ni], 0, 0, 0);
            accX[ni] = __builtin_amdgcn_mfma_f32_16x16x32_f16(al, bh, accX[ni], 0, 0, 0);
        }
    }

    const float invs = 1.0f / 2048.0f;
    #pragma unroll
    for (int ni = 0; ni < 4; ++ni) {
        const int k = w * 64 + ni * 16 + (lane & 15);
        const float cn = cnorm[k];
        #pragma unroll
        for (int r = 0; r < 4; ++r) {
            const int rl = (lane >> 4) * 4 + r;
            const float S = acc[ni][r] + accX[ni][r] * invs;
            D[rl * 257 + k] = enorm[b0 + rl] - 2.0f * S + cn;
        }
    }
    __syncthreads();

    #pragma unroll
    for (int rr = 0; rr < 4; ++rr) {
        const int r = w * 4 + rr;
        const float d0 = D[r * 257 + lane +   0];
        const float d1 = D[r * 257 + lane +  64];
        const float d2 = D[r * 257 + lane + 128];
        const float d3 = D[r * 257 + lane + 192];
        float mn = fminf(fminf(d0, d1), fminf(d2, d3));
        #pragma unroll
        for (int off = 32; off >= 1; off >>= 1) mn = fminf(mn, __shfl_xor(mn, off, 64));
        float s = expf(-ALPHA_F * (d0 - mn)) + expf(-ALPHA_F * (d1 - mn))
                + expf(-ALPHA_F * (d2 - mn)) + expf(-ALPHA_F * (d3 - mn));
        #pragma unroll
        for (int off = 32; off >= 1; off >>= 1) s += __shfl_xor(s, off, 64);
        if (lane == 0) { MINV[r] = mn; SUMV[r] = s; }
    }
    __syncthreads();

    const int b = t & 15, kg = t >> 4;
    const float mn = MINV[b], sv = SUMV[b];
    #pragma unroll
    for (int kk = 0; kk < 16; ++kk) {
        const int k = kk * 16 + kg;
        const float dv = D[b * 257 + k];
        out[(size_t)k * 8192 + b0 + b] = dv * expf(-ALPHA_F * (dv - mn)) / sv;
    }
}

// ============ recon — double-buffered single-barrier pipeline ===============
// Same restructure as emb_gemm; MFMA order and epilogue bit-identical.
__global__ __launch_bounds__(256) void recon_gemm(
    const _Float16* __restrict__ embh, const _Float16* __restrict__ Wdh,
    const float* __restrict__ b_dec, float* __restrict__ out)
{
    __shared__ _Float16 Ah[2][8 * 64 * 8];
    __shared__ _Float16 Bh[2][8 * 64 * 8];
    const int t = threadIdx.x, lane = t & 63, w = t >> 6;
    const int wm = w >> 1, wn = w & 1;
    const int nb = blockIdx.x, mb = blockIdx.y;

    floatx4 acc[4][4] = {};

    // prologue: stage kc=0 into buffer 0
    #pragma unroll
    for (int i = 0; i < 2; ++i) {
        const int c = w * 2 + i;
        gload_lds16(embh + (size_t)(((mb * 8 + c) * 8 + 0) * 64 + lane) * 8, &Ah[0][c * 512]);
        gload_lds16(Wdh + (size_t)((0 * 128 + nb * 8 + c) * 64 + lane) * 8, &Bh[0][c * 512]);
    }
    __syncthreads();

    for (int kc = 0; kc < 8; ++kc) {
        const int buf = kc & 1;
        if (kc < 7) {
            #pragma unroll
            for (int i = 0; i < 2; ++i) {
                const int c = w * 2 + i;
                gload_lds16(embh + (size_t)(((mb * 8 + c) * 8 + (kc + 1)) * 64 + lane) * 8,
                            &Ah[buf ^ 1][c * 512]);
                gload_lds16(Wdh + (size_t)(((kc + 1) * 128 + nb * 8 + c) * 64 + lane) * 8,
                            &Bh[buf ^ 1][c * 512]);
            }
        }
        half8 a[4], b[4];
        #pragma unroll
        for (int mi = 0; mi < 4; ++mi) a[mi] = *(const half8*)(&Ah[buf][((wm * 4 + mi) * 64 + lane) * 8]);
        #pragma unroll
        for (int ni = 0; ni < 4; ++ni) b[ni] = *(const half8*)(&Bh[buf][((wn * 4 + ni) * 64 + lane) * 8]);
        #pragma unroll
        for (int mi = 0; mi < 4; ++mi)
            #pragma unroll
            for (int ni = 0; ni < 4; ++ni)
                acc[mi][ni] = __builtin_amdgcn_mfma_f32_16x16x32_f16(a[mi], b[ni], acc[mi][ni], 0, 0, 0);
        if (kc < 7) __syncthreads();
    }

    #pragma unroll
    for (int ni = 0; ni < 4; ++ni) {
        const int col = nb * 128 + (wn * 4 + ni) * 16 + (lane & 15);
        const float bias = b_dec[col];
        #pragma unroll
        for (int mi = 0; mi < 4; ++mi) {
            const int rowBase = mb * 128 + (wm * 4 + mi) * 16 + (lane >> 4) * 4;
            #pragma unroll
            for (int r = 0; r < 4; ++r)
                out[(size_t)(rowBase + r) * 2048 + col] = acc[mi][ni][r] + bias;
        }
    }
}

// ================= launch ==================================================
extern "C" void kernel_launch(void* const* d_in, const int* in_sizes, int n_in,
                              void* d_out, int out_size, void* d_ws, size_t ws_size,
                              hipStream_t stream) {
    const float* x     = (const float*)d_in[0];   // [8192,2048]
    const float* W_enc = (const float*)d_in[1];   // [2048,256]
    const float* b_enc = (const float*)d_in[2];   // [256]
    const float* W_dec = (const float*)d_in[3];   // [256,2048]
    const float* b_dec = (const float*)d_in[4];   // [2048]
    const float* creps = (const float*)d_in[5];   // [256,256]

    float* out_w   = (float*)d_out;               // [256,8192]
    float* out_rec = out_w + (size_t)256 * 8192;  // [8192,2048]
    float* P       = out_rec;                     // split-K partials (32MB of 64MB)

    float*     cnorm = (float*)d_ws;                       // 1 KB
    _Float16*  embh  = (_Float16*)(cnorm + 256);           // 4 MB, frag-order
    _Float16*  Whf   = embh + (size_t)8192 * 256;          // 1 MB
    _Float16*  Wlf   = Whf + (size_t)2048 * 256;           // 1 MB
    _Float16*  Wdh   = Wlf + (size_t)2048 * 256;           // 1 MB
    _Float16*  crh   = Wdh + (size_t)256 * 2048;           // 128 KB
    _Float16*  crl   = crh + (size_t)256 * 256;            // 128 KB
    float*     enorm = (float*)(crl + (size_t)256 * 256);  // 32 KB
    float*     embf  = enorm + 8192;                       // 8 MB fp32 row-major

    prep<<<608, 256, 0, stream>>>(W_enc, W_dec, creps, Whf, Wlf, Wdh, crh, crl, cnorm);

    emb_gemm<<<dim3(4, 128), 256, 0, stream>>>(x, Whf, Wlf, P);

    finalize<<<256, 256, 0, stream>>>(P, b_enc, embh, embf, enorm);

    dist16<<<512, 256, 0, stream>>>(embf, crh, crl, enorm, cnorm, out_w);

    recon_gemm<<<dim3(16, 64), 256, 0, stream>>>(embh, Wdh, b_dec, out_rec);
}

// Round 3
// 195.936 us; speedup vs baseline: 1.0594x; 1.0246x over previous
//
#include <hip/hip_runtime.h>

#define ALPHA_F 1000.0f

typedef _Float16 half8 __attribute__((ext_vector_type(8)));
typedef float floatx4 __attribute__((ext_vector_type(4)));

// ============ fused prep: W_enc/W_dec/creps splits + cnorm (unchanged) =====
__global__ __launch_bounds__(256) void prep(
    const float* __restrict__ W_enc, const float* __restrict__ W_dec,
    const float* __restrict__ creps,
    _Float16* __restrict__ Wh, _Float16* __restrict__ Wl,
    _Float16* __restrict__ Wdh,
    _Float16* __restrict__ Ch, _Float16* __restrict__ Cl,
    float* __restrict__ cnorm)
{
    const int bid = blockIdx.x;
    if (bid < 256) {
        const int q = bid * 256 + threadIdx.x;
        const int n = q & 255, k8 = q >> 8;
        const int k = k8 * 8;
        half8 h, l;
        #pragma unroll
        for (int i = 0; i < 8; ++i) {
            const float v = W_enc[(size_t)(k + i) * 256 + n] * 256.0f;
            const _Float16 hi = (_Float16)v;
            h[i] = hi;
            l[i] = (_Float16)(v - (float)hi);
        }
        const int kc = k >> 5, nt = n >> 4;
        const int lane = (n & 15) | ((k8 & 3) << 4);
        const size_t idx = (size_t)((kc * 16 + nt) * 64 + lane) * 8;
        *(half8*)(Wh + idx) = h;
        *(half8*)(Wl + idx) = l;
    } else if (bid < 512) {
        const int q = (bid - 256) * 256 + threadIdx.x;
        const int n = q & 2047, k8 = q >> 11;
        const int k = k8 * 8;
        half8 h;
        #pragma unroll
        for (int i = 0; i < 8; ++i) h[i] = (_Float16)W_dec[(size_t)(k + i) * 2048 + n];
        const int kc = k8 >> 2, nt = n >> 4;
        const int lane = (n & 15) | ((k8 & 3) << 4);
        *(half8*)(Wdh + (size_t)((kc * 128 + nt) * 64 + lane) * 8) = h;
    } else if (bid < 544) {
        const int q = (bid - 512) * 256 + threadIdx.x;
        const int n = q & 255, j8 = q >> 8;
        const int j = j8 * 8;
        half8 h, l;
        #pragma unroll
        for (int i = 0; i < 8; ++i) {
            const float v = creps[(size_t)n * 256 + j + i];
            const _Float16 hi = (_Float16)v;
            h[i] = hi;
            l[i] = (_Float16)((v - (float)hi) * 2048.0f);
        }
        const int jc = j >> 5, nt = n >> 4;
        const int lane = (n & 15) | ((j8 & 3) << 4);
        const size_t idx = (size_t)((jc * 16 + nt) * 64 + lane) * 8;
        *(half8*)(Ch + idx) = h;
        *(half8*)(Cl + idx) = l;
    } else {
        const int wid = threadIdx.x >> 6, lane = threadIdx.x & 63;
        const int row = (bid - 544) * 4 + wid;
        const float4 v = *(const float4*)(creps + (size_t)row * 256 + lane * 4);
        float s = v.x * v.x + v.y * v.y + v.z * v.z + v.w * v.w;
        #pragma unroll
        for (int off = 32; off >= 1; off >>= 1) s += __shfl_xor(s, off, 64);
        if (lane == 0) cnorm[row] = s;
    }
}

// ============ emb partials — B direct from L2, raw barriers ================
// B (Whf/Wlf, 2MB, L2-resident) is already in per-lane fragment layout ->
// loaded straight to VGPRs, prefetched one K-step ahead; these plain VGPR
// loads stay in flight across the raw s_barrier (no __syncthreads vmcnt(0)
// drain). Only the A tile (fp32->hi/lo, shared by 4 waves) uses LDS: 16 KB
// double-buffered, one raw barrier + lgkmcnt(0) per K-step.
// MFMA chain order, conversion formulas, P layout bit-identical to r3.
__global__ __launch_bounds__(256) void emb_gemm(
    const float* __restrict__ x, const _Float16* __restrict__ Wh,
    const _Float16* __restrict__ Wl, float* __restrict__ P)
{
    __shared__ _Float16 Ah[2][2048], Al[2][2048];
    const int t = threadIdx.x, lane = t & 63, w = t >> 6;
    const int kk = blockIdx.x;
    const int mb = blockIdx.y;
    const int m0 = mb * 64;

    const int am = t >> 2, q = t & 3;
    const int aoff = (((am >> 4) * 64) + ((am & 15) | (q << 4))) * 8;
    const float* xP = x + (size_t)(m0 + am) * 2048 + kk * 512 + q * 8;

    // B fragment base for this wave: Wh + ((kk*256 + it*16 + w*4+ni)*64 + lane)*8
    const _Float16* bhP = Wh + (size_t)((kk * 256 + w * 4) * 64 + lane) * 8;
    const _Float16* blP = Wl + (size_t)((kk * 256 + w * 4) * 64 + lane) * 8;

    floatx4 acc[4][4] = {};
    half8 bh[4], bl[4];

    // --- prologue: stage A(0) to LDS, load B(0) to regs ---
    {
        const float4 v0 = *(const float4*)(xP);
        const float4 v1 = *(const float4*)(xP + 4);
        const float vv[8] = {v0.x, v0.y, v0.z, v0.w, v1.x, v1.y, v1.z, v1.w};
        half8 h8, l8;
        #pragma unroll
        for (int i = 0; i < 8; ++i) {
            const _Float16 hi = (_Float16)vv[i];
            h8[i] = hi;
            l8[i] = (_Float16)(vv[i] - (float)hi);
        }
        *(half8*)(&Ah[0][aoff]) = h8;
        *(half8*)(&Al[0][aoff]) = l8;
        #pragma unroll
        for (int ni = 0; ni < 4; ++ni) {
            bh[ni] = *(const half8*)(bhP + ni * 512);
            bl[ni] = *(const half8*)(blP + ni * 512);
        }
        asm volatile("s_waitcnt lgkmcnt(0)" ::: "memory");
        __builtin_amdgcn_sched_barrier(0);
        __builtin_amdgcn_s_barrier();
    }

    #pragma unroll 2
    for (int it = 0; it < 16; ++it) {
        const int buf = it & 1;

        // prefetch next: x -> regs, B frags -> regs (stay in flight under MFMAs)
        float4 n0, n1;
        half8 nbh[4], nbl[4];
        if (it < 15) {
            n0 = *(const float4*)(xP + (it + 1) * 32);
            n1 = *(const float4*)(xP + (it + 1) * 32 + 4);
            #pragma unroll
            for (int ni = 0; ni < 4; ++ni) {
                nbh[ni] = *(const half8*)(bhP + (size_t)(it + 1) * 8192 + ni * 512);
                nbl[ni] = *(const half8*)(blP + (size_t)(it + 1) * 8192 + ni * 512);
            }
        }

        // current A frags from LDS
        half8 ah[4], al[4];
        #pragma unroll
        for (int s = 0; s < 4; ++s) {
            ah[s] = *(const half8*)(&Ah[buf][(s * 64 + lane) * 8]);
            al[s] = *(const half8*)(&Al[buf][(s * 64 + lane) * 8]);
        }

        #pragma unroll
        for (int mi = 0; mi < 4; ++mi) {
            #pragma unroll
            for (int ni = 0; ni < 4; ++ni) {
                acc[mi][ni] = __builtin_amdgcn_mfma_f32_16x16x32_f16(ah[mi], bl[ni], acc[mi][ni], 0, 0, 0);
                acc[mi][ni] = __builtin_amdgcn_mfma_f32_16x16x32_f16(al[mi], bh[ni], acc[mi][ni], 0, 0, 0);
                acc[mi][ni] = __builtin_amdgcn_mfma_f32_16x16x32_f16(ah[mi], bh[ni], acc[mi][ni], 0, 0, 0);
            }
        }

        if (it < 15) {
            // convert + write next A tile, rotate B regs, one raw barrier
            const float vv[8] = {n0.x, n0.y, n0.z, n0.w, n1.x, n1.y, n1.z, n1.w};
            half8 h8, l8;
            #pragma unroll
            for (int i = 0; i < 8; ++i) {
                const _Float16 hi = (_Float16)vv[i];
                h8[i] = hi;
                l8[i] = (_Float16)(vv[i] - (float)hi);
            }
            *(half8*)(&Ah[buf ^ 1][aoff]) = h8;
            *(half8*)(&Al[buf ^ 1][aoff]) = l8;
            #pragma unroll
            for (int ni = 0; ni < 4; ++ni) { bh[ni] = nbh[ni]; bl[ni] = nbl[ni]; }
            asm volatile("s_waitcnt lgkmcnt(0)" ::: "memory");
            __builtin_amdgcn_sched_barrier(0);
            __builtin_amdgcn_s_barrier();
        }
    }

    float* Pk = P + (size_t)kk * 2097152;
    #pragma unroll
    for (int mi = 0; mi < 4; ++mi) {
        #pragma unroll
        for (int ni = 0; ni < 4; ++ni) {
            const int col = w * 64 + ni * 16 + (lane & 15);
            const int rowBase = m0 + mi * 16 + (lane >> 4) * 4;
            #pragma unroll
            for (int r = 0; r < 4; ++r)
                Pk[(size_t)(rowBase + r) * 256 + col] = acc[mi][ni][r];
        }
    }
}

// ============ finalize (unchanged) ==========================================
__global__ __launch_bounds__(256) void finalize(
    const float* __restrict__ P, const float* __restrict__ b_enc,
    _Float16* __restrict__ ehg, float* __restrict__ embf,
    float* __restrict__ enorm)
{
    const int t = threadIdx.x;
    const int b0 = blockIdx.x * 32;
    const int row = t >> 3, c8 = t & 7;
    const int grow = b0 + row;

    const float* p0 = P + (size_t)grow * 256 + c8 * 32;
    float4 v[8];
    #pragma unroll
    for (int i = 0; i < 8; ++i) v[i] = *(const float4*)(p0 + i * 4);
    #pragma unroll
    for (int kk = 1; kk < 4; ++kk) {
        const float* pk = p0 + (size_t)kk * 2097152;
        #pragma unroll
        for (int i = 0; i < 8; ++i) {
            const float4 a = *(const float4*)(pk + i * 4);
            v[i].x += a.x; v[i].y += a.y; v[i].z += a.z; v[i].w += a.w;
        }
    }
    const float inv = 1.0f / 256.0f;
    float e[32];
    float ssq = 0.0f;
    #pragma unroll
    for (int i = 0; i < 8; ++i) {
        const float4 b = *(const float4*)(b_enc + c8 * 32 + i * 4);
        e[i * 4 + 0] = v[i].x * inv + b.x;
        e[i * 4 + 1] = v[i].y * inv + b.y;
        e[i * 4 + 2] = v[i].z * inv + b.z;
        e[i * 4 + 3] = v[i].w * inv + b.w;
        ssq += e[i * 4 + 0] * e[i * 4 + 0];
        ssq += e[i * 4 + 1] * e[i * 4 + 1];
        ssq += e[i * 4 + 2] * e[i * 4 + 2];
        ssq += e[i * 4 + 3] * e[i * 4 + 3];
    }
    #pragma unroll
    for (int i = 0; i < 8; ++i) {
        float4 s4;
        s4.x = e[i * 4 + 0]; s4.y = e[i * 4 + 1];
        s4.z = e[i * 4 + 2]; s4.w = e[i * 4 + 3];
        *(float4*)(embf + (size_t)grow * 256 + c8 * 32 + i * 4) = s4;
    }
    #pragma unroll
    for (int oo = 0; oo < 4; ++oo) {
        const int q = c8 * 4 + oo;
        half8 h;
        #pragma unroll
        for (int i = 0; i < 8; ++i) h[i] = (_Float16)e[oo * 8 + i];
        const size_t idx = (size_t)(((grow >> 4) * 8 + (q >> 2)) * 64
                                    + ((grow & 15) | ((q & 3) << 4))) * 8;
        *(half8*)(ehg + idx) = h;
    }
    ssq += __shfl_xor(ssq, 1, 64);
    ssq += __shfl_xor(ssq, 2, 64);
    ssq += __shfl_xor(ssq, 4, 64);
    if (c8 == 0) enorm[grow] = ssq;
}

// ============ dist + softmin (unchanged) ====================================
__global__ __launch_bounds__(256) void dist16(
    const float* __restrict__ embf, const _Float16* __restrict__ ch,
    const _Float16* __restrict__ cl, const float* __restrict__ enorm,
    const float* __restrict__ cnorm, float* __restrict__ out)
{
    __shared__ float D[16 * 257];
    __shared__ float MINV[16], SUMV[16];
    const int t = threadIdx.x, lane = t & 63, w = t >> 6;
    const int b0 = blockIdx.x * 16;
    const int arow16 = lane & 15, aoct = lane >> 4;

    floatx4 acc[4] = {}, accX[4] = {};
    for (int kc = 0; kc < 8; ++kc) {
        const float* fp = embf + (size_t)(b0 + arow16) * 256 + kc * 32 + aoct * 8;
        const float4 u0 = *(const float4*)(fp);
        const float4 u1 = *(const float4*)(fp + 4);
        const float vv[8] = {u0.x, u0.y, u0.z, u0.w, u1.x, u1.y, u1.z, u1.w};
        half8 ah, al;
        #pragma unroll
        for (int j = 0; j < 8; ++j) {
            const _Float16 hi = (_Float16)vv[j];
            ah[j] = hi;
            al[j] = (_Float16)((vv[j] - (float)hi) * 2048.0f);
        }
        #pragma unroll
        for (int ni = 0; ni < 4; ++ni) {
            const size_t bb = (size_t)((kc * 16 + (w * 4 + ni)) * 64 + lane) * 8;
            const half8 bh = *(const half8*)(ch + bb);
            const half8 bl = *(const half8*)(cl + bb);
            acc[ni]  = __builtin_amdgcn_mfma_f32_16x16x32_f16(ah, bh, acc[ni], 0, 0, 0);
            accX[ni] = __builtin_amdgcn_mfma_f32_16x16x32_f16(ah, bl, accX[ni], 0, 0, 0);
            accX[ni] = __builtin_amdgcn_mfma_f32_16x16x32_f16(al, bh, accX[ni], 0, 0, 0);
        }
    }

    const float invs = 1.0f / 2048.0f;
    #pragma unroll
    for (int ni = 0; ni < 4; ++ni) {
        const int k = w * 64 + ni * 16 + (lane & 15);
        const float cn = cnorm[k];
        #pragma unroll
        for (int r = 0; r < 4; ++r) {
            const int rl = (lane >> 4) * 4 + r;
            const float S = acc[ni][r] + accX[ni][r] * invs;
            D[rl * 257 + k] = enorm[b0 + rl] - 2.0f * S + cn;
        }
    }
    __syncthreads();

    #pragma unroll
    for (int rr = 0; rr < 4; ++rr) {
        const int r = w * 4 + rr;
        const float d0 = D[r * 257 + lane +   0];
        const float d1 = D[r * 257 + lane +  64];
        const float d2 = D[r * 257 + lane + 128];
        const float d3 = D[r * 257 + lane + 192];
        float mn = fminf(fminf(d0, d1), fminf(d2, d3));
        #pragma unroll
        for (int off = 32; off >= 1; off >>= 1) mn = fminf(mn, __shfl_xor(mn, off, 64));
        float s = expf(-ALPHA_F * (d0 - mn)) + expf(-ALPHA_F * (d1 - mn))
                + expf(-ALPHA_F * (d2 - mn)) + expf(-ALPHA_F * (d3 - mn));
        #pragma unroll
        for (int off = 32; off >= 1; off >>= 1) s += __shfl_xor(s, off, 64);
        if (lane == 0) { MINV[r] = mn; SUMV[r] = s; }
    }
    __syncthreads();

    const int b = t & 15, kg = t >> 4;
    const float mn = MINV[b], sv = SUMV[b];
    #pragma unroll
    for (int kk = 0; kk < 16; ++kk) {
        const int k = kk * 16 + kg;
        const float dv = D[b * 257 + k];
        out[(size_t)k * 8192 + b0 + b] = dv * expf(-ALPHA_F * (dv - mn)) / sv;
    }
}

// ============ recon — LDS-free, barrier-free register GEMM ==================
// Both operands already live in global memory in the exact per-lane fragment
// layout (16B/lane contiguous, L2-resident: embh 4MB, Wdh 1MB). Each wave
// loads its fragments straight to VGPRs; no LDS, no barriers, waves fully
// independent -> compiler pipelines loads across kc freely.
// MFMA order and epilogue bit-identical to the staged version.
__global__ __launch_bounds__(256) void recon_gemm(
    const _Float16* __restrict__ embh, const _Float16* __restrict__ Wdh,
    const float* __restrict__ b_dec, float* __restrict__ out)
{
    const int t = threadIdx.x, lane = t & 63, w = t >> 6;
    const int wm = w >> 1, wn = w & 1;
    const int nb = blockIdx.x, mb = blockIdx.y;

    floatx4 acc[4][4] = {};

    #pragma unroll
    for (int kc = 0; kc < 8; ++kc) {
        half8 a[4], b[4];
        #pragma unroll
        for (int mi = 0; mi < 4; ++mi)
            a[mi] = *(const half8*)(embh + (size_t)(((mb * 8 + wm * 4 + mi) * 8 + kc) * 64 + lane) * 8);
        #pragma unroll
        for (int ni = 0; ni < 4; ++ni)
            b[ni] = *(const half8*)(Wdh + (size_t)((kc * 128 + nb * 8 + wn * 4 + ni) * 64 + lane) * 8);
        #pragma unroll
        for (int mi = 0; mi < 4; ++mi)
            #pragma unroll
            for (int ni = 0; ni < 4; ++ni)
                acc[mi][ni] = __builtin_amdgcn_mfma_f32_16x16x32_f16(a[mi], b[ni], acc[mi][ni], 0, 0, 0);
    }

    #pragma unroll
    for (int ni = 0; ni < 4; ++ni) {
        const int col = nb * 128 + (wn * 4 + ni) * 16 + (lane & 15);
        const float bias = b_dec[col];
        #pragma unroll
        for (int mi = 0; mi < 4; ++mi) {
            const int rowBase = mb * 128 + (wm * 4 + mi) * 16 + (lane >> 4) * 4;
            #pragma unroll
            for (int r = 0; r < 4; ++r)
                out[(size_t)(rowBase + r) * 2048 + col] = acc[mi][ni][r] + bias;
        }
    }
}

// ================= launch ==================================================
extern "C" void kernel_launch(void* const* d_in, const int* in_sizes, int n_in,
                              void* d_out, int out_size, void* d_ws, size_t ws_size,
                              hipStream_t stream) {
    const float* x     = (const float*)d_in[0];   // [8192,2048]
    const float* W_enc = (const float*)d_in[1];   // [2048,256]
    const float* b_enc = (const float*)d_in[2];   // [256]
    const float* W_dec = (const float*)d_in[3];   // [256,2048]
    const float* b_dec = (const float*)d_in[4];   // [2048]
    const float* creps = (const float*)d_in[5];   // [256,256]

    float* out_w   = (float*)d_out;               // [256,8192]
    float* out_rec = out_w + (size_t)256 * 8192;  // [8192,2048]
    float* P       = out_rec;                     // split-K partials (32MB of 64MB)

    float*     cnorm = (float*)d_ws;                       // 1 KB
    _Float16*  embh  = (_Float16*)(cnorm + 256);           // 4 MB, frag-order
    _Float16*  Whf   = embh + (size_t)8192 * 256;          // 1 MB
    _Float16*  Wlf   = Whf + (size_t)2048 * 256;           // 1 MB
    _Float16*  Wdh   = Wlf + (size_t)2048 * 256;           // 1 MB
    _Float16*  crh   = Wdh + (size_t)256 * 2048;           // 128 KB
    _Float16*  crl   = crh + (size_t)256 * 256;            // 128 KB
    float*     enorm = (float*)(crl + (size_t)256 * 256);  // 32 KB
    float*     embf  = enorm + 8192;                       // 8 MB fp32 row-major

    prep<<<608, 256, 0, stream>>>(W_enc, W_dec, creps, Whf, Wlf, Wdh, crh, crl, cnorm);

    emb_gemm<<<dim3(4, 128), 256, 0, stream>>>(x, Whf, Wlf, P);

    finalize<<<256, 256, 0, stream>>>(P, b_enc, embh, embf, enorm);

    dist16<<<512, 256, 0, stream>>>(embf, crh, crl, enorm, cnorm, out_w);

    recon_gemm<<<dim3(16, 64), 256, 0, stream>>>(embh, Wdh, b_dec, out_rec);
}